// Round 18
// baseline (1220.085 us; speedup 1.0000x reference)
//
#include <hip/hip_runtime.h>
#include <hip/hip_bf16.h>

// ---------------------------------------------------------------------------
// SMN forward. B=512 U=10 L=50 E=200 H=200 V=50000
// r17 pipeline + register-patch conv phase in match_conv_pool.
// ---------------------------------------------------------------------------

typedef __attribute__((ext_vector_type(8))) short short8v;   // 8 bf16 (4 VGPR)
typedef __attribute__((ext_vector_type(4))) float f32x4;

__device__ __forceinline__ float sigm(float x) { return 1.0f / (1.0f + __expf(-x)); }
__device__ __forceinline__ float tanhfast(float x) {
    float e = __expf(2.0f * x);
    return 1.0f - 2.0f / (e + 1.0f);
}
__device__ __forceinline__ float bl(unsigned x) { return __uint_as_float(x << 16); }
__device__ __forceinline__ float bh(unsigned x) { return __uint_as_float(x & 0xffff0000u); }
__device__ __forceinline__ unsigned packbf(float a, float b) {
    union { __hip_bfloat16 h[2]; unsigned u; } cv;
    cv.h[0] = __float2bfloat16(a); cv.h[1] = __float2bfloat16(b);
    return cv.u;
}

// ---------------------------------------------------------------------------
// emb16 = bf16(emb), one pass. 10M elements as 5M bf16-pairs.
// ---------------------------------------------------------------------------
__global__ __launch_bounds__(256)
void conv_emb16(const float* __restrict__ emb, __hip_bfloat16* __restrict__ emb16)
{
    int idx = blockIdx.x * 256 + threadIdx.x;
    if (idx < 5000000) {
        float2 v = *(const float2*)(emb + (size_t)idx * 2);
        ((unsigned*)emb16)[idx] = packbf(v.x, v.y);
    }
}

// ---------------------------------------------------------------------------
// MFMA GEMM (K=200 specialized): C16[M,N] = bf16(A[M,200] @ W[N,200]^T + bias)
// ---------------------------------------------------------------------------
__global__ __launch_bounds__(256)
void gemm_mfma(const void* __restrict__ Asrc, int a_bf16,
               const int* __restrict__ gidx,
               const float* __restrict__ W, const float* __restrict__ bias,
               __hip_bfloat16* __restrict__ C, int M, int N)
{
    __shared__ __hip_bfloat16 Al[64 * 232];
    __shared__ __hip_bfloat16 Bl[64 * 232];
    const int tid = threadIdx.x;
    const int m0 = blockIdx.x * 64, n0 = blockIdx.y * 64;

    for (int idx = tid; idx < 64 * 29; idx += 256) {
        int r = idx / 29, q = idx - r * 29;
        int k0 = q * 8, row = m0 + r;
        uint4 val = make_uint4(0, 0, 0, 0);
        if (k0 < 200 && row < M) {
            size_t ar = (size_t)(gidx ? gidx[row] : row) * 200 + k0;
            if (a_bf16) {
                val = *(const uint4*)((const __hip_bfloat16*)Asrc + ar);
            } else {
                const float* ap = (const float*)Asrc + ar;
                float4 f0 = *(const float4*)ap;
                float4 f1 = *(const float4*)(ap + 4);
                val.x = packbf(f0.x, f0.y); val.y = packbf(f0.z, f0.w);
                val.z = packbf(f1.x, f1.y); val.w = packbf(f1.z, f1.w);
            }
        }
        *(uint4*)(Al + r * 232 + k0) = val;
    }
    for (int idx = tid; idx < 64 * 29; idx += 256) {
        int r = idx / 29, q = idx - r * 29;
        int k0 = q * 8, row = n0 + r;
        uint4 val = make_uint4(0, 0, 0, 0);
        if (k0 < 200 && row < N) {
            const float* wp = W + (size_t)row * 200 + k0;
            float4 f0 = *(const float4*)wp;
            float4 f1 = *(const float4*)(wp + 4);
            val.x = packbf(f0.x, f0.y); val.y = packbf(f0.z, f0.w);
            val.z = packbf(f1.x, f1.y); val.w = packbf(f1.z, f1.w);
        }
        *(uint4*)(Bl + r * 232 + k0) = val;
    }
    __syncthreads();

    const int wid = tid >> 6, lane = tid & 63;
    const int wm = (wid >> 1) * 32, wn = (wid & 1) * 32;
    const int lrow = lane & 15, lk8 = (lane >> 4) * 8;
    f32x4 acc00 = {0.f, 0.f, 0.f, 0.f}, acc01 = {0.f, 0.f, 0.f, 0.f};
    f32x4 acc10 = {0.f, 0.f, 0.f, 0.f}, acc11 = {0.f, 0.f, 0.f, 0.f};
#pragma unroll
    for (int kk = 0; kk < 7; ++kk) {
        const int kb = kk * 32 + lk8;
        short8v a0 = *(const short8v*)(Al + (wm + lrow) * 232 + kb);
        short8v a1 = *(const short8v*)(Al + (wm + 16 + lrow) * 232 + kb);
        short8v b0 = *(const short8v*)(Bl + (wn + lrow) * 232 + kb);
        short8v b1 = *(const short8v*)(Bl + (wn + 16 + lrow) * 232 + kb);
        acc00 = __builtin_amdgcn_mfma_f32_16x16x32_bf16(a0, b0, acc00, 0, 0, 0);
        acc01 = __builtin_amdgcn_mfma_f32_16x16x32_bf16(a0, b1, acc01, 0, 0, 0);
        acc10 = __builtin_amdgcn_mfma_f32_16x16x32_bf16(a1, b0, acc10, 0, 0, 0);
        acc11 = __builtin_amdgcn_mfma_f32_16x16x32_bf16(a1, b1, acc11, 0, 0, 0);
    }
    const int drow = (lane >> 4) * 4, dcol = lane & 15;
#pragma unroll
    for (int fm = 0; fm < 2; ++fm) {
#pragma unroll
        for (int fn = 0; fn < 2; ++fn) {
            const f32x4 av = (fm == 0) ? (fn == 0 ? acc00 : acc01)
                                       : (fn == 0 ? acc10 : acc11);
            const int gcol = n0 + wn + fn * 16 + dcol;
            if (gcol >= N) continue;
            const float bs = bias ? bias[gcol] : 0.0f;
#pragma unroll
            for (int r = 0; r < 4; ++r) {
                const int grow = m0 + wm + fm * 16 + drow + r;
                if (grow >= M) continue;
                C[(size_t)grow * N + gcol] = __float2bfloat16(av[r] + bs);
            }
        }
    }
}

// ---------------------------------------------------------------------------
// General-K MFMA GEMM: C[M,N] = act(A[M,K] @ W[N,K]^T + bias)
// ---------------------------------------------------------------------------
__global__ __launch_bounds__(256)
void gemm_mfma_k(const void* __restrict__ Asrc, int a_bf16,
                 const float* __restrict__ W, const float* __restrict__ bias,
                 void* __restrict__ Cv, int c_bf16,
                 int M, int N, int K, int act)
{
    __shared__ __align__(16) __hip_bfloat16 As[64 * 136];
    __shared__ __align__(16) __hip_bfloat16 Bs[64 * 136];
    const int tid = threadIdx.x;
    const int m0 = blockIdx.x * 64, n0 = blockIdx.y * 64;
    const int wid = tid >> 6, lane = tid & 63;
    const int wm = (wid >> 1) * 32, wn = (wid & 1) * 32;
    const int lrow = lane & 15, lk8 = (lane >> 4) * 8;
    const bool aAlign16 = a_bf16 && ((K & 7) == 0);

    f32x4 acc00 = {0.f, 0.f, 0.f, 0.f}, acc01 = {0.f, 0.f, 0.f, 0.f};
    f32x4 acc10 = {0.f, 0.f, 0.f, 0.f}, acc11 = {0.f, 0.f, 0.f, 0.f};

    for (int kb = 0; kb < K; kb += 128) {
        for (int idx = tid; idx < 1024; idx += 256) {
            int r = idx >> 4, q = idx & 15;
            int k0 = kb + q * 8, row = m0 + r;
            uint4 av = make_uint4(0, 0, 0, 0);
            if (row < M && k0 < K) {
                size_t base = (size_t)row * K + k0;
                if (a_bf16) {
                    const __hip_bfloat16* ap = (const __hip_bfloat16*)Asrc + base;
                    if (aAlign16 && k0 + 8 <= K) {
                        av = *(const uint4*)ap;
                    } else {
                        unsigned t4[4] = {0, 0, 0, 0};
                        int nv = (K - k0 < 8) ? (K - k0) : 8;
                        for (int e = 0; e < nv; ++e)
                            ((__hip_bfloat16*)t4)[e] = ap[e];
                        av.x = t4[0]; av.y = t4[1]; av.z = t4[2]; av.w = t4[3];
                    }
                } else {
                    const float* ap = (const float*)Asrc + base;
                    float tv[8] = {0, 0, 0, 0, 0, 0, 0, 0};
                    int nv = (K - k0 < 8) ? (K - k0) : 8;
                    for (int e = 0; e < nv; ++e) tv[e] = ap[e];
                    av.x = packbf(tv[0], tv[1]); av.y = packbf(tv[2], tv[3]);
                    av.z = packbf(tv[4], tv[5]); av.w = packbf(tv[6], tv[7]);
                }
            }
            *(uint4*)(As + r * 136 + q * 8) = av;
        }
        for (int idx = tid; idx < 1024; idx += 256) {
            int r = idx >> 4, q = idx & 15;
            int k0 = kb + q * 8, row = n0 + r;
            uint4 bv = make_uint4(0, 0, 0, 0);
            if (row < N && k0 < K) {
                const float* wp = W + (size_t)row * K + k0;
                float tv[8] = {0, 0, 0, 0, 0, 0, 0, 0};
                int nv = (K - k0 < 8) ? (K - k0) : 8;
                for (int e = 0; e < nv; ++e) tv[e] = wp[e];
                bv.x = packbf(tv[0], tv[1]); bv.y = packbf(tv[2], tv[3]);
                bv.z = packbf(tv[4], tv[5]); bv.w = packbf(tv[6], tv[7]);
            }
            *(uint4*)(Bs + r * 136 + q * 8) = bv;
        }
        __syncthreads();
#pragma unroll
        for (int kk = 0; kk < 4; ++kk) {
            const int ko = kk * 32 + lk8;
            short8v a0 = *(const short8v*)(As + (wm + lrow) * 136 + ko);
            short8v a1 = *(const short8v*)(As + (wm + 16 + lrow) * 136 + ko);
            short8v b0 = *(const short8v*)(Bs + (wn + lrow) * 136 + ko);
            short8v b1 = *(const short8v*)(Bs + (wn + 16 + lrow) * 136 + ko);
            acc00 = __builtin_amdgcn_mfma_f32_16x16x32_bf16(a0, b0, acc00, 0, 0, 0);
            acc01 = __builtin_amdgcn_mfma_f32_16x16x32_bf16(a0, b1, acc01, 0, 0, 0);
            acc10 = __builtin_amdgcn_mfma_f32_16x16x32_bf16(a1, b0, acc10, 0, 0, 0);
            acc11 = __builtin_amdgcn_mfma_f32_16x16x32_bf16(a1, b1, acc11, 0, 0, 0);
        }
        __syncthreads();
    }

    const int drow = (lane >> 4) * 4, dcol = lane & 15;
#pragma unroll
    for (int fm = 0; fm < 2; ++fm) {
#pragma unroll
        for (int fn = 0; fn < 2; ++fn) {
            const f32x4 av = (fm == 0) ? (fn == 0 ? acc00 : acc01)
                                       : (fn == 0 ? acc10 : acc11);
            const int gcol = n0 + wn + fn * 16 + dcol;
            if (gcol >= N) continue;
            const float bs = bias ? bias[gcol] : 0.0f;
#pragma unroll
            for (int r = 0; r < 4; ++r) {
                const int grow = m0 + wm + fm * 16 + drow + r;
                if (grow >= M) continue;
                float t = av[r] + bs;
                if (act == 1) t = tanhfast(t);
                if (c_bf16) ((__hip_bfloat16*)Cv)[(size_t)grow * N + gcol] = __float2bfloat16(t);
                else        ((float*)Cv)[(size_t)grow * N + gcol] = t;
            }
        }
    }
}

// ---------------------------------------------------------------------------
// WT_f[200][600] = W_hh_f[600][200]^T  (final GRU only)
// ---------------------------------------------------------------------------
__global__ __launch_bounds__(256)
void transpose_wf(const float* __restrict__ Wf, float* __restrict__ Tf)
{
    int id = blockIdx.x * 256 + threadIdx.x;
    if (id < 120000) {
        int e = id / 600, j = id - e * 600;
        Tf[id] = Wf[(size_t)j * 200 + e];
    }
}

// ---------------------------------------------------------------------------
// Pack Whh [600][200] f32 -> [640][224] bf16, zero-padded (both GRUs)
// ---------------------------------------------------------------------------
__global__ __launch_bounds__(256)
void pack_whh(const float* __restrict__ Wu, const float* __restrict__ Wr,
              __hip_bfloat16* __restrict__ Du, __hip_bfloat16* __restrict__ Dr)
{
    int idx = blockIdx.x * 256 + threadIdx.x;     // 640*224 = 143360
    if (idx >= 143360) return;
    int j = idx / 224, e = idx - j * 224;
    bool v = (j < 600) && (e < 200);
    Du[idx] = __float2bfloat16(v ? Wu[(size_t)j * 200 + e] : 0.0f);
    Dr[idx] = __float2bfloat16(v ? Wr[(size_t)j * 200 + e] : 0.0f);
}

// ---------------------------------------------------------------------------
// MFMA persistent GRU scan (r13 config: best measured, 355us).
// ---------------------------------------------------------------------------
__global__ __launch_bounds__(512, 2)
void scan_gru_mfma(const int* __restrict__ utt,
                   const __hip_bfloat16* __restrict__ EPu,
                   const __hip_bfloat16* __restrict__ xpr16,
                   const __hip_bfloat16* __restrict__ Wu16,
                   const __hip_bfloat16* __restrict__ Wr16,
                   const float* __restrict__ bhu, const float* __restrict__ bhr,
                   __hip_bfloat16* __restrict__ ug16,
                   __hip_bfloat16* __restrict__ rg16)
{
    __shared__ __align__(16) float gh[32][644];            // 82432 B
    __shared__ __align__(16) float hf[32][204];            // 26112 B
    __shared__ __align__(16) __hip_bfloat16 h16[32][232];  // 14848 B

    const int tid = threadIdx.x;
    const bool isResp = (int)blockIdx.x >= 160;
    const int row0 = isResp ? ((int)blockIdx.x - 160) * 32 : (int)blockIdx.x * 32;
    const __hip_bfloat16* Wt = isResp ? Wr16 : Wu16;
    const float* bgate = isResp ? bhr : bhu;
    __hip_bfloat16* arch = isResp ? rg16 : ug16;

    for (int i = tid; i < 32 * 204; i += 512) ((float*)hf)[i] = 0.0f;
    for (int i = tid; i < 928; i += 512) ((uint4*)h16)[i] = make_uint4(0, 0, 0, 0);
    __syncthreads();

    const int wid = tid >> 6, lane = tid & 63;
    const int lrow = lane & 15, lk8 = (lane >> 4) * 8;
    const int drow = (lane >> 4) * 4, dcol = lane & 15;

    // ---- preload W fragments into registers (invariant over t) ----
    short8v Bf[5][7];
#pragma unroll
    for (int i = 0; i < 5; ++i) {
        const int j = (wid * 5 + i) * 16 + lrow;
#pragma unroll
        for (int kk = 0; kk < 7; ++kk)
            Bf[i][kk] = *(const short8v*)(Wt + (size_t)j * 224 + kk * 32 + lk8);
    }

    // gate task 0: rows 0..20; task 1 (tid<288): rows 20..31
    const int r0a = tid / 25,        c0a = (tid % 25) * 8;
    const int t1  = tid + 512;
    const int r0b = t1 / 25,         c0b = (t1 % 25) * 8;

    for (int t = 0; t < 50; ++t) {
        // ---- prefetch xp for BOTH gate tasks (hidden under MFMA phase) ----
        const int ga = row0 + r0a;
        const __hip_bfloat16* xpa = isResp
            ? (xpr16 + ((size_t)ga * 50 + t) * 600)
            : (EPu + (size_t)utt[ga * 50 + t] * 600);
        uint4 xra = *(const uint4*)(xpa + c0a);
        uint4 xza = *(const uint4*)(xpa + 200 + c0a);
        uint4 xna = *(const uint4*)(xpa + 400 + c0a);
        uint4 xrb, xzb, xnb;
        const int gb = row0 + r0b;
        if (tid < 288) {
            const __hip_bfloat16* xpb = isResp
                ? (xpr16 + ((size_t)gb * 50 + t) * 600)
                : (EPu + (size_t)utt[gb * 50 + t] * 600);
            xrb = *(const uint4*)(xpb + c0b);
            xzb = *(const uint4*)(xpb + 200 + c0b);
            xnb = *(const uint4*)(xpb + 400 + c0b);
        }

        // ---- MFMA phase: gh = h16 @ W^T (register B) ----
        f32x4 a0[5], a1[5];
#pragma unroll
        for (int i = 0; i < 5; ++i) {
            a0[i] = (f32x4){0.f, 0.f, 0.f, 0.f};
            a1[i] = (f32x4){0.f, 0.f, 0.f, 0.f};
        }
#pragma unroll
        for (int kk = 0; kk < 7; ++kk) {
            short8v A0 = *(const short8v*)(&h16[lrow][kk * 32 + lk8]);
            short8v A1 = *(const short8v*)(&h16[16 + lrow][kk * 32 + lk8]);
#pragma unroll
            for (int i = 0; i < 5; ++i) {
                a0[i] = __builtin_amdgcn_mfma_f32_16x16x32_bf16(A0, Bf[i][kk], a0[i], 0, 0, 0);
                a1[i] = __builtin_amdgcn_mfma_f32_16x16x32_bf16(A1, Bf[i][kk], a1[i], 0, 0, 0);
            }
        }
#pragma unroll
        for (int i = 0; i < 5; ++i) {
            const int j = (wid * 5 + i) * 16 + dcol;
#pragma unroll
            for (int r = 0; r < 4; ++r) {
                gh[drow + r][j] = a0[i][r];
                gh[16 + drow + r][j] = a1[i][r];
            }
        }
        __syncthreads();

        // ---- gate phase ----
        {   // task 0 (prefetched)
            const int row = r0a, c0 = c0a, grow = ga;
            const unsigned xr4[4] = { xra.x, xra.y, xra.z, xra.w };
            const unsigned xz4[4] = { xza.x, xza.y, xza.z, xza.w };
            const unsigned xn4[4] = { xna.x, xna.y, xna.z, xna.w };
            float hn[8];
#pragma unroll
            for (int j = 0; j < 8; ++j) {
                const int c = c0 + j;
                const float xr = (j & 1) ? bh(xr4[j >> 1]) : bl(xr4[j >> 1]);
                const float xz = (j & 1) ? bh(xz4[j >> 1]) : bl(xz4[j >> 1]);
                const float xn = (j & 1) ? bh(xn4[j >> 1]) : bl(xn4[j >> 1]);
                const float rr = sigm(xr + gh[row][c] + bgate[c]);
                const float zz = sigm(xz + gh[row][200 + c] + bgate[200 + c]);
                const float nn = tanhfast(xn + rr * (gh[row][400 + c] + bgate[400 + c]));
                hn[j] = (1.0f - zz) * nn + zz * hf[row][c];
            }
            *(float4*)(&hf[row][c0])     = (float4){hn[0], hn[1], hn[2], hn[3]};
            *(float4*)(&hf[row][c0 + 4]) = (float4){hn[4], hn[5], hn[6], hn[7]};
            uint4 pk;
            pk.x = packbf(hn[0], hn[1]); pk.y = packbf(hn[2], hn[3]);
            pk.z = packbf(hn[4], hn[5]); pk.w = packbf(hn[6], hn[7]);
            *(uint4*)(&h16[row][c0]) = pk;
            *(uint4*)(arch + ((size_t)grow * 50 + t) * 200 + c0) = pk;
        }
        if (tid < 288) {   // task 1 (prefetched)
            const int row = r0b, c0 = c0b, grow = gb;
            const unsigned xr4[4] = { xrb.x, xrb.y, xrb.z, xrb.w };
            const unsigned xz4[4] = { xzb.x, xzb.y, xzb.z, xzb.w };
            const unsigned xn4[4] = { xnb.x, xnb.y, xnb.z, xnb.w };
            float hn[8];
#pragma unroll
            for (int j = 0; j < 8; ++j) {
                const int c = c0 + j;
                const float xr = (j & 1) ? bh(xr4[j >> 1]) : bl(xr4[j >> 1]);
                const float xz = (j & 1) ? bh(xz4[j >> 1]) : bl(xz4[j >> 1]);
                const float xn = (j & 1) ? bh(xn4[j >> 1]) : bl(xn4[j >> 1]);
                const float rr = sigm(xr + gh[row][c] + bgate[c]);
                const float zz = sigm(xz + gh[row][200 + c] + bgate[200 + c]);
                const float nn = tanhfast(xn + rr * (gh[row][400 + c] + bgate[400 + c]));
                hn[j] = (1.0f - zz) * nn + zz * hf[row][c];
            }
            *(float4*)(&hf[row][c0])     = (float4){hn[0], hn[1], hn[2], hn[3]};
            *(float4*)(&hf[row][c0 + 4]) = (float4){hn[4], hn[5], hn[6], hn[7]};
            uint4 pk;
            pk.x = packbf(hn[0], hn[1]); pk.y = packbf(hn[2], hn[3]);
            pk.z = packbf(hn[4], hn[5]); pk.w = packbf(hn[6], hn[7]);
            *(uint4*)(&h16[row][c0]) = pk;
            *(uint4*)(arch + ((size_t)grow * 50 + t) * 200 + c0) = pk;
        }
        __syncthreads();
    }
}

// ---------------------------------------------------------------------------
// Fused m1/m2 match (MFMA) + conv3x3(2->8)+relu+maxpool3x3 per (b,u).
// Conv phase: channel c == k per unrolled iteration; weights + 5x5x2 input
// patch hoisted to registers (LDS reads 324 -> 68 per output, same math).
// ---------------------------------------------------------------------------
__global__ __launch_bounds__(256)
void match_conv_pool(const int* __restrict__ utt, const int* __restrict__ resp,
                     const __hip_bfloat16* __restrict__ emb16,
                     const __hip_bfloat16* __restrict__ ug16,
                     const __hip_bfloat16* __restrict__ rgA16,
                     const float* __restrict__ cw, const float* __restrict__ cb,
                     __hip_bfloat16* __restrict__ pooled16)
{
    const int bu = blockIdx.x, b = bu / 10;
    __shared__ __align__(16) __hip_bfloat16 As[64 * 232];
    __shared__ __align__(16) __hip_bfloat16 Bs[64 * 232];
    __shared__ float m[2][50][50];
    __shared__ float w[144];
    __shared__ float bsh[8];
    const int tid = threadIdx.x;
    if (tid < 144) w[tid] = cw[tid];
    if (tid >= 144 && tid < 152) bsh[tid - 144] = cb[tid - 144];

    for (int idx = tid; idx < 64 * 29; idx += 256) {
        int r = idx / 29, q = idx - r * 29;
        uint4 av = make_uint4(0, 0, 0, 0), bv = make_uint4(0, 0, 0, 0);
        if (r < 50 && q < 25) {
            av = *(const uint4*)(emb16 + (size_t)utt[bu * 50 + r] * 200 + q * 8);
            bv = *(const uint4*)(emb16 + (size_t)resp[b * 50 + r] * 200 + q * 8);
        }
        *(uint4*)(As + r * 232 + q * 8) = av;
        *(uint4*)(Bs + r * 232 + q * 8) = bv;
    }
    __syncthreads();

    const int wid = tid >> 6, lane = tid & 63;
    const int wm = (wid >> 1) * 32, wn = (wid & 1) * 32;
    const int lrow = lane & 15, lk8 = (lane >> 4) * 8;
    const int drow = (lane >> 4) * 4, dcol = lane & 15;

#pragma unroll 1
    for (int ch = 0; ch < 2; ++ch) {
        f32x4 acc00 = {0.f, 0.f, 0.f, 0.f}, acc01 = {0.f, 0.f, 0.f, 0.f};
        f32x4 acc10 = {0.f, 0.f, 0.f, 0.f}, acc11 = {0.f, 0.f, 0.f, 0.f};
#pragma unroll
        for (int kk = 0; kk < 7; ++kk) {
            const int kb = kk * 32 + lk8;
            short8v a0 = *(const short8v*)(As + (wm + lrow) * 232 + kb);
            short8v a1 = *(const short8v*)(As + (wm + 16 + lrow) * 232 + kb);
            short8v b0 = *(const short8v*)(Bs + (wn + lrow) * 232 + kb);
            short8v b1 = *(const short8v*)(Bs + (wn + 16 + lrow) * 232 + kb);
            acc00 = __builtin_amdgcn_mfma_f32_16x16x32_bf16(a0, b0, acc00, 0, 0, 0);
            acc01 = __builtin_amdgcn_mfma_f32_16x16x32_bf16(a0, b1, acc01, 0, 0, 0);
            acc10 = __builtin_amdgcn_mfma_f32_16x16x32_bf16(a1, b0, acc10, 0, 0, 0);
            acc11 = __builtin_amdgcn_mfma_f32_16x16x32_bf16(a1, b1, acc11, 0, 0, 0);
        }
#pragma unroll
        for (int fm = 0; fm < 2; ++fm) {
#pragma unroll
            for (int fn = 0; fn < 2; ++fn) {
                const f32x4 av = (fm == 0) ? (fn == 0 ? acc00 : acc01)
                                           : (fn == 0 ? acc10 : acc11);
                const int gcol = wn + fn * 16 + dcol;
                if (gcol >= 50) continue;
#pragma unroll
                for (int r = 0; r < 4; ++r) {
                    const int grow = wm + fm * 16 + drow + r;
                    if (grow < 50) m[ch][grow][gcol] = av[r];
                }
            }
        }
        __syncthreads();
        if (ch == 0) {
            for (int idx = tid; idx < 50 * 25; idx += 256) {
                int r = idx / 25, q = idx - r * 25;
                *(uint4*)(As + r * 232 + q * 8) =
                    *(const uint4*)(ug16 + (size_t)bu * 10000 + (size_t)r * 200 + q * 8);
                *(uint4*)(Bs + r * 232 + q * 8) =
                    *(const uint4*)(rgA16 + (size_t)b * 10000 + (size_t)r * 200 + q * 8);
            }
            __syncthreads();
        }
    }

    // ---- conv + relu + maxpool (register patch; c == k for tid<256) ----
    const int ph = (tid >> 4) & 15, pw = tid & 15;
#pragma unroll
    for (int k = 0; k < 8; ++k) {
        const int o = tid + k * 256;
        float wr[18];
#pragma unroll
        for (int i = 0; i < 18; ++i) wr[i] = w[k * 18 + i];
        const float bsv = bsh[k];
        float patch[2][5][5];
#pragma unroll
        for (int ci = 0; ci < 2; ++ci)
#pragma unroll
            for (int y = 0; y < 5; ++y)
#pragma unroll
                for (int x = 0; x < 5; ++x)
                    patch[ci][y][x] = m[ci][ph * 3 + y][pw * 3 + x];
        float mx = -1e30f;
#pragma unroll
        for (int p = 0; p < 3; ++p)
#pragma unroll
            for (int q = 0; q < 3; ++q) {
                float s = bsv;
#pragma unroll
                for (int ci = 0; ci < 2; ++ci)
#pragma unroll
                    for (int dy = 0; dy < 3; ++dy)
#pragma unroll
                        for (int dx = 0; dx < 3; ++dx)
                            s = fmaf(wr[ci * 9 + dy * 3 + dx],
                                     patch[ci][p + dy][q + dx], s);
                s = fmaxf(s, 0.0f);
                mx = fmaxf(mx, s);
            }
        pooled16[(size_t)bu * 2048 + o] = __float2bfloat16(mx);
    }
}

// ---------------------------------------------------------------------------
__global__ __launch_bounds__(256)
void final_gru(const float* __restrict__ xpf, const float* __restrict__ WTf,
               const float* __restrict__ bhf, const float* __restrict__ fw,
               const float* __restrict__ fb, float* __restrict__ out)
{
    const int blk = blockIdx.x;
    const int tid = threadIdx.x;
    __shared__ float h[2][201];
    for (int i = tid; i < 402; i += 256) ((float*)h)[i] = 0.0f;
    __syncthreads();
    const int rr = tid / 100;
    const int j0 = 2 * (tid % 100);
    for (int t = 0; t < 10; ++t) {
        float cR[2] = {}, cZ[2] = {}, cN[2] = {};
        if (tid < 200) {
#pragma unroll 2
            for (int e = 0; e < 200; ++e) {
                const float* w = WTf + (size_t)e * 600;
                float2 wr = *(const float2*)(w + j0);
                float2 wz = *(const float2*)(w + 200 + j0);
                float2 wn = *(const float2*)(w + 400 + j0);
                float hv = h[rr][e];
                cR[0] = fmaf(hv, wr.x, cR[0]); cR[1] = fmaf(hv, wr.y, cR[1]);
                cZ[0] = fmaf(hv, wz.x, cZ[0]); cZ[1] = fmaf(hv, wz.y, cZ[1]);
                cN[0] = fmaf(hv, wn.x, cN[0]); cN[1] = fmaf(hv, wn.y, cN[1]);
            }
        }
        __syncthreads();
        if (tid < 200) {
            const float* xp = xpf + ((size_t)(blk * 2 + rr) * 10 + t) * 600;
#pragma unroll
            for (int j = 0; j < 2; ++j) {
                const int c = j0 + j;
                float rrg = sigm(xp[c] + cR[j] + bhf[c]);
                float zz = sigm(xp[200 + c] + cZ[j] + bhf[200 + c]);
                float nn = tanhfast(xp[400 + c] + rrg * (cN[j] + bhf[400 + c]));
                h[rr][c] = (1.0f - zz) * nn + zz * h[rr][c];
            }
        }
        __syncthreads();
    }
    if (tid < 2) {
        float s = fb[0];
        for (int k = 0; k < 200; ++k) s = fmaf(h[tid][k], fw[k], s);
        out[blk * 2 + tid] = sigm(s);
    }
}

__global__ __launch_bounds__(256)
void fill_out(float* __restrict__ out)
{
    int i = blockIdx.x * 256 + threadIdx.x;
    if (i < 512) out[i] = 0.0f;
}

// ---------------------------------------------------------------------------
extern "C" void kernel_launch(void* const* d_in, const int* in_sizes, int n_in,
                              void* d_out, int out_size, void* d_ws, size_t ws_size,
                              hipStream_t stream)
{
    const int*   utt    = (const int*)d_in[0];
    const int*   resp   = (const int*)d_in[1];
    const float* emb    = (const float*)d_in[2];
    const float* W_ih_u = (const float*)d_in[3];
    const float* W_hh_u = (const float*)d_in[4];
    const float* b_ih_u = (const float*)d_in[5];
    const float* b_hh_u = (const float*)d_in[6];
    const float* W_ih_r = (const float*)d_in[7];
    const float* W_hh_r = (const float*)d_in[8];
    const float* b_ih_r = (const float*)d_in[9];
    const float* b_hh_r = (const float*)d_in[10];
    const float* conv_w = (const float*)d_in[11];
    const float* conv_b = (const float*)d_in[12];
    const float* lin_w  = (const float*)d_in[13];
    const float* lin_b  = (const float*)d_in[14];
    const float* Amat   = (const float*)d_in[15];
    const float* W_ih_f = (const float*)d_in[16];
    const float* W_hh_f = (const float*)d_in[17];
    const float* b_ih_f = (const float*)d_in[18];
    const float* b_hh_f = (const float*)d_in[19];
    const float* flin_w = (const float*)d_in[20];
    const float* flin_b = (const float*)d_in[21];
    float* out = (float*)d_out;
    float* ws  = (float*)d_ws;

    size_t off = 0;
    auto alloc = [&](size_t n) { float* p = ws + off; off += (n + 63) & ~((size_t)63); return p; };
    float* WT_f   = alloc(120000);
    float* Wu16f  = alloc(71680);      // [640,224] bf16
    float* Wr16f  = alloc(71680);      // [640,224] bf16
    float* emb16f = alloc(5000000);    // [50000,200] bf16 = 20 MB
    float* EPuf   = alloc(15000000);   // [50000,600] bf16; post-scan: pooled16
    float* xprf   = alloc(7680000);    // [25600,600] bf16; post-scan: mv16/xpf
    float* ug16f  = alloc(25600000);   // [5120,50,200] bf16
    float* rg16f  = alloc(2560000);    // [512,50,200] bf16
    float* rgA16f = alloc(2560000);    // [25600,200] bf16
    // total ~58.7M floats = 235 MB

    if (off * sizeof(float) > ws_size) {
        hipLaunchKernelGGL(fill_out, dim3(2), dim3(256), 0, stream, out);
        return;
    }

    __hip_bfloat16* Wu16  = (__hip_bfloat16*)Wu16f;
    __hip_bfloat16* Wr16  = (__hip_bfloat16*)Wr16f;
    __hip_bfloat16* emb16 = (__hip_bfloat16*)emb16f;
    __hip_bfloat16* EPu   = (__hip_bfloat16*)EPuf;
    __hip_bfloat16* xpr16 = (__hip_bfloat16*)xprf;
    __hip_bfloat16* ug16  = (__hip_bfloat16*)ug16f;
    __hip_bfloat16* rg16  = (__hip_bfloat16*)rg16f;
    __hip_bfloat16* rgA16 = (__hip_bfloat16*)rgA16f;
    __hip_bfloat16* pooled16 = (__hip_bfloat16*)EPuf;   // [5120,2048] bf16 (EPu dead)
    __hip_bfloat16* mv16     = (__hip_bfloat16*)xprf;   // [5120,50] bf16 (xpr dead)
    float* xpf = xprf + 400000;                          // [5120,600] f32

    // 1. one-pass conversions: W_hh_f transpose, Whh bf16 pack, emb bf16
    hipLaunchKernelGGL(transpose_wf, dim3(469), dim3(256), 0, stream, W_hh_f, WT_f);
    hipLaunchKernelGGL(pack_whh, dim3(560), dim3(256), 0, stream,
                       W_hh_u, W_hh_r, Wu16, Wr16);
    hipLaunchKernelGGL(conv_emb16, dim3(19532), dim3(256), 0, stream, emb, emb16);
    // 2. EPu = bf16(emb16 @ W_ih_u^T + b_ih_u)  [MFMA, bf16 A]
    hipLaunchKernelGGL(gemm_mfma, dim3(782, 10), dim3(256), 0, stream,
                       (const void*)emb16, 1, (const int*)nullptr, W_ih_u, b_ih_u,
                       EPu, 50000, 600);
    // 3. xpr16 = bf16(emb16[resp] @ W_ih_r^T + b_ih_r)  [MFMA, bf16 A gather]
    hipLaunchKernelGGL(gemm_mfma, dim3(400, 10), dim3(256), 0, stream,
                       (const void*)emb16, 1, resp, W_ih_r, b_ih_r,
                       xpr16, 25600, 600);
    // 4. persistent MFMA dual-GRU scan (r13 config)
    hipLaunchKernelGGL(scan_gru_mfma, dim3(176), dim3(512), 0, stream,
                       utt, EPu, xpr16, Wu16, Wr16, b_hh_u, b_hh_r, ug16, rg16);
    // 5. rgA16 = bf16(rg @ Amat^T)  [MFMA]
    hipLaunchKernelGGL(gemm_mfma, dim3(400, 4), dim3(256), 0, stream,
                       (const void*)rg16, 1, (const int*)nullptr, Amat,
                       (const float*)nullptr, rgA16, 25600, 200);
    // 6. fused match (MFMA, emb16-gathered operands) + conv + pool
    hipLaunchKernelGGL(match_conv_pool, dim3(5120), dim3(256), 0, stream,
                       utt, resp, emb16, ug16, rgA16, conv_w, conv_b, pooled16);
    // 7. mv16 = tanh(pooled16 @ lin_w^T + lin_b)  [MFMA, K=2048]
    hipLaunchKernelGGL(gemm_mfma_k, dim3(80, 1), dim3(256), 0, stream,
                       (const void*)pooled16, 1, lin_w, lin_b,
                       (void*)mv16, 1, 5120, 50, 2048, 1);
    // 8. xpf = mv16 @ W_ih_f^T + b_ih_f  [MFMA, K=50]
    hipLaunchKernelGGL(gemm_mfma_k, dim3(80, 10), dim3(256), 0, stream,
                       (const void*)mv16, 1, W_ih_f, b_ih_f,
                       (void*)xpf, 0, 5120, 600, 50, 0);
    // 9. final GRU + logit + sigmoid
    hipLaunchKernelGGL(final_gru, dim3(256), dim3(256), 0, stream,
                       xpf, WT_f, b_hh_f, flin_w, flin_b, out);
}

// Round 19
// 1122.698 us; speedup vs baseline: 1.0867x; 1.0867x over previous
//
#include <hip/hip_runtime.h>
#include <hip/hip_bf16.h>

// ---------------------------------------------------------------------------
// SMN forward. B=512 U=10 L=50 E=200 H=200 V=50000
// r17 configuration (measured best: 1127 us). emb16 single-conversion,
// MFMA everywhere, r13 scan config.
// ---------------------------------------------------------------------------

typedef __attribute__((ext_vector_type(8))) short short8v;   // 8 bf16 (4 VGPR)
typedef __attribute__((ext_vector_type(4))) float f32x4;

__device__ __forceinline__ float sigm(float x) { return 1.0f / (1.0f + __expf(-x)); }
__device__ __forceinline__ float tanhfast(float x) {
    float e = __expf(2.0f * x);
    return 1.0f - 2.0f / (e + 1.0f);
}
__device__ __forceinline__ float bl(unsigned x) { return __uint_as_float(x << 16); }
__device__ __forceinline__ float bh(unsigned x) { return __uint_as_float(x & 0xffff0000u); }
__device__ __forceinline__ unsigned packbf(float a, float b) {
    union { __hip_bfloat16 h[2]; unsigned u; } cv;
    cv.h[0] = __float2bfloat16(a); cv.h[1] = __float2bfloat16(b);
    return cv.u;
}

// ---------------------------------------------------------------------------
// emb16 = bf16(emb), one pass. 10M elements as 5M bf16-pairs.
// ---------------------------------------------------------------------------
__global__ __launch_bounds__(256)
void conv_emb16(const float* __restrict__ emb, __hip_bfloat16* __restrict__ emb16)
{
    int idx = blockIdx.x * 256 + threadIdx.x;
    if (idx < 5000000) {
        float2 v = *(const float2*)(emb + (size_t)idx * 2);
        ((unsigned*)emb16)[idx] = packbf(v.x, v.y);
    }
}

// ---------------------------------------------------------------------------
// MFMA GEMM (K=200 specialized): C16[M,N] = bf16(A[M,200] @ W[N,200]^T + bias)
// ---------------------------------------------------------------------------
__global__ __launch_bounds__(256)
void gemm_mfma(const void* __restrict__ Asrc, int a_bf16,
               const int* __restrict__ gidx,
               const float* __restrict__ W, const float* __restrict__ bias,
               __hip_bfloat16* __restrict__ C, int M, int N)
{
    __shared__ __hip_bfloat16 Al[64 * 232];
    __shared__ __hip_bfloat16 Bl[64 * 232];
    const int tid = threadIdx.x;
    const int m0 = blockIdx.x * 64, n0 = blockIdx.y * 64;

    for (int idx = tid; idx < 64 * 29; idx += 256) {
        int r = idx / 29, q = idx - r * 29;
        int k0 = q * 8, row = m0 + r;
        uint4 val = make_uint4(0, 0, 0, 0);
        if (k0 < 200 && row < M) {
            size_t ar = (size_t)(gidx ? gidx[row] : row) * 200 + k0;
            if (a_bf16) {
                val = *(const uint4*)((const __hip_bfloat16*)Asrc + ar);
            } else {
                const float* ap = (const float*)Asrc + ar;
                float4 f0 = *(const float4*)ap;
                float4 f1 = *(const float4*)(ap + 4);
                val.x = packbf(f0.x, f0.y); val.y = packbf(f0.z, f0.w);
                val.z = packbf(f1.x, f1.y); val.w = packbf(f1.z, f1.w);
            }
        }
        *(uint4*)(Al + r * 232 + k0) = val;
    }
    for (int idx = tid; idx < 64 * 29; idx += 256) {
        int r = idx / 29, q = idx - r * 29;
        int k0 = q * 8, row = n0 + r;
        uint4 val = make_uint4(0, 0, 0, 0);
        if (k0 < 200 && row < N) {
            const float* wp = W + (size_t)row * 200 + k0;
            float4 f0 = *(const float4*)wp;
            float4 f1 = *(const float4*)(wp + 4);
            val.x = packbf(f0.x, f0.y); val.y = packbf(f0.z, f0.w);
            val.z = packbf(f1.x, f1.y); val.w = packbf(f1.z, f1.w);
        }
        *(uint4*)(Bl + r * 232 + k0) = val;
    }
    __syncthreads();

    const int wid = tid >> 6, lane = tid & 63;
    const int wm = (wid >> 1) * 32, wn = (wid & 1) * 32;
    const int lrow = lane & 15, lk8 = (lane >> 4) * 8;
    f32x4 acc00 = {0.f, 0.f, 0.f, 0.f}, acc01 = {0.f, 0.f, 0.f, 0.f};
    f32x4 acc10 = {0.f, 0.f, 0.f, 0.f}, acc11 = {0.f, 0.f, 0.f, 0.f};
#pragma unroll
    for (int kk = 0; kk < 7; ++kk) {
        const int kb = kk * 32 + lk8;
        short8v a0 = *(const short8v*)(Al + (wm + lrow) * 232 + kb);
        short8v a1 = *(const short8v*)(Al + (wm + 16 + lrow) * 232 + kb);
        short8v b0 = *(const short8v*)(Bl + (wn + lrow) * 232 + kb);
        short8v b1 = *(const short8v*)(Bl + (wn + 16 + lrow) * 232 + kb);
        acc00 = __builtin_amdgcn_mfma_f32_16x16x32_bf16(a0, b0, acc00, 0, 0, 0);
        acc01 = __builtin_amdgcn_mfma_f32_16x16x32_bf16(a0, b1, acc01, 0, 0, 0);
        acc10 = __builtin_amdgcn_mfma_f32_16x16x32_bf16(a1, b0, acc10, 0, 0, 0);
        acc11 = __builtin_amdgcn_mfma_f32_16x16x32_bf16(a1, b1, acc11, 0, 0, 0);
    }
    const int drow = (lane >> 4) * 4, dcol = lane & 15;
#pragma unroll
    for (int fm = 0; fm < 2; ++fm) {
#pragma unroll
        for (int fn = 0; fn < 2; ++fn) {
            const f32x4 av = (fm == 0) ? (fn == 0 ? acc00 : acc01)
                                       : (fn == 0 ? acc10 : acc11);
            const int gcol = n0 + wn + fn * 16 + dcol;
            if (gcol >= N) continue;
            const float bs = bias ? bias[gcol] : 0.0f;
#pragma unroll
            for (int r = 0; r < 4; ++r) {
                const int grow = m0 + wm + fm * 16 + drow + r;
                if (grow >= M) continue;
                C[(size_t)grow * N + gcol] = __float2bfloat16(av[r] + bs);
            }
        }
    }
}

// ---------------------------------------------------------------------------
// General-K MFMA GEMM: C[M,N] = act(A[M,K] @ W[N,K]^T + bias)
// ---------------------------------------------------------------------------
__global__ __launch_bounds__(256)
void gemm_mfma_k(const void* __restrict__ Asrc, int a_bf16,
                 const float* __restrict__ W, const float* __restrict__ bias,
                 void* __restrict__ Cv, int c_bf16,
                 int M, int N, int K, int act)
{
    __shared__ __align__(16) __hip_bfloat16 As[64 * 136];
    __shared__ __align__(16) __hip_bfloat16 Bs[64 * 136];
    const int tid = threadIdx.x;
    const int m0 = blockIdx.x * 64, n0 = blockIdx.y * 64;
    const int wid = tid >> 6, lane = tid & 63;
    const int wm = (wid >> 1) * 32, wn = (wid & 1) * 32;
    const int lrow = lane & 15, lk8 = (lane >> 4) * 8;
    const bool aAlign16 = a_bf16 && ((K & 7) == 0);

    f32x4 acc00 = {0.f, 0.f, 0.f, 0.f}, acc01 = {0.f, 0.f, 0.f, 0.f};
    f32x4 acc10 = {0.f, 0.f, 0.f, 0.f}, acc11 = {0.f, 0.f, 0.f, 0.f};

    for (int kb = 0; kb < K; kb += 128) {
        for (int idx = tid; idx < 1024; idx += 256) {
            int r = idx >> 4, q = idx & 15;
            int k0 = kb + q * 8, row = m0 + r;
            uint4 av = make_uint4(0, 0, 0, 0);
            if (row < M && k0 < K) {
                size_t base = (size_t)row * K + k0;
                if (a_bf16) {
                    const __hip_bfloat16* ap = (const __hip_bfloat16*)Asrc + base;
                    if (aAlign16 && k0 + 8 <= K) {
                        av = *(const uint4*)ap;
                    } else {
                        unsigned t4[4] = {0, 0, 0, 0};
                        int nv = (K - k0 < 8) ? (K - k0) : 8;
                        for (int e = 0; e < nv; ++e)
                            ((__hip_bfloat16*)t4)[e] = ap[e];
                        av.x = t4[0]; av.y = t4[1]; av.z = t4[2]; av.w = t4[3];
                    }
                } else {
                    const float* ap = (const float*)Asrc + base;
                    float tv[8] = {0, 0, 0, 0, 0, 0, 0, 0};
                    int nv = (K - k0 < 8) ? (K - k0) : 8;
                    for (int e = 0; e < nv; ++e) tv[e] = ap[e];
                    av.x = packbf(tv[0], tv[1]); av.y = packbf(tv[2], tv[3]);
                    av.z = packbf(tv[4], tv[5]); av.w = packbf(tv[6], tv[7]);
                }
            }
            *(uint4*)(As + r * 136 + q * 8) = av;
        }
        for (int idx = tid; idx < 1024; idx += 256) {
            int r = idx >> 4, q = idx & 15;
            int k0 = kb + q * 8, row = n0 + r;
            uint4 bv = make_uint4(0, 0, 0, 0);
            if (row < N && k0 < K) {
                const float* wp = W + (size_t)row * K + k0;
                float tv[8] = {0, 0, 0, 0, 0, 0, 0, 0};
                int nv = (K - k0 < 8) ? (K - k0) : 8;
                for (int e = 0; e < nv; ++e) tv[e] = wp[e];
                bv.x = packbf(tv[0], tv[1]); bv.y = packbf(tv[2], tv[3]);
                bv.z = packbf(tv[4], tv[5]); bv.w = packbf(tv[6], tv[7]);
            }
            *(uint4*)(Bs + r * 136 + q * 8) = bv;
        }
        __syncthreads();
#pragma unroll
        for (int kk = 0; kk < 4; ++kk) {
            const int ko = kk * 32 + lk8;
            short8v a0 = *(const short8v*)(As + (wm + lrow) * 136 + ko);
            short8v a1 = *(const short8v*)(As + (wm + 16 + lrow) * 136 + ko);
            short8v b0 = *(const short8v*)(Bs + (wn + lrow) * 136 + ko);
            short8v b1 = *(const short8v*)(Bs + (wn + 16 + lrow) * 136 + ko);
            acc00 = __builtin_amdgcn_mfma_f32_16x16x32_bf16(a0, b0, acc00, 0, 0, 0);
            acc01 = __builtin_amdgcn_mfma_f32_16x16x32_bf16(a0, b1, acc01, 0, 0, 0);
            acc10 = __builtin_amdgcn_mfma_f32_16x16x32_bf16(a1, b0, acc10, 0, 0, 0);
            acc11 = __builtin_amdgcn_mfma_f32_16x16x32_bf16(a1, b1, acc11, 0, 0, 0);
        }
        __syncthreads();
    }

    const int drow = (lane >> 4) * 4, dcol = lane & 15;
#pragma unroll
    for (int fm = 0; fm < 2; ++fm) {
#pragma unroll
        for (int fn = 0; fn < 2; ++fn) {
            const f32x4 av = (fm == 0) ? (fn == 0 ? acc00 : acc01)
                                       : (fn == 0 ? acc10 : acc11);
            const int gcol = n0 + wn + fn * 16 + dcol;
            if (gcol >= N) continue;
            const float bs = bias ? bias[gcol] : 0.0f;
#pragma unroll
            for (int r = 0; r < 4; ++r) {
                const int grow = m0 + wm + fm * 16 + drow + r;
                if (grow >= M) continue;
                float t = av[r] + bs;
                if (act == 1) t = tanhfast(t);
                if (c_bf16) ((__hip_bfloat16*)Cv)[(size_t)grow * N + gcol] = __float2bfloat16(t);
                else        ((float*)Cv)[(size_t)grow * N + gcol] = t;
            }
        }
    }
}

// ---------------------------------------------------------------------------
// WT_f[200][600] = W_hh_f[600][200]^T  (final GRU only)
// ---------------------------------------------------------------------------
__global__ __launch_bounds__(256)
void transpose_wf(const float* __restrict__ Wf, float* __restrict__ Tf)
{
    int id = blockIdx.x * 256 + threadIdx.x;
    if (id < 120000) {
        int e = id / 600, j = id - e * 600;
        Tf[id] = Wf[(size_t)j * 200 + e];
    }
}

// ---------------------------------------------------------------------------
// Pack Whh [600][200] f32 -> [640][224] bf16, zero-padded (both GRUs)
// ---------------------------------------------------------------------------
__global__ __launch_bounds__(256)
void pack_whh(const float* __restrict__ Wu, const float* __restrict__ Wr,
              __hip_bfloat16* __restrict__ Du, __hip_bfloat16* __restrict__ Dr)
{
    int idx = blockIdx.x * 256 + threadIdx.x;     // 640*224 = 143360
    if (idx >= 143360) return;
    int j = idx / 224, e = idx - j * 224;
    bool v = (j < 600) && (e < 200);
    Du[idx] = __float2bfloat16(v ? Wu[(size_t)j * 200 + e] : 0.0f);
    Dr[idx] = __float2bfloat16(v ? Wr[(size_t)j * 200 + e] : 0.0f);
}

// ---------------------------------------------------------------------------
// MFMA persistent GRU scan (r13 config: best measured, 355us).
// ---------------------------------------------------------------------------
__global__ __launch_bounds__(512, 2)
void scan_gru_mfma(const int* __restrict__ utt,
                   const __hip_bfloat16* __restrict__ EPu,
                   const __hip_bfloat16* __restrict__ xpr16,
                   const __hip_bfloat16* __restrict__ Wu16,
                   const __hip_bfloat16* __restrict__ Wr16,
                   const float* __restrict__ bhu, const float* __restrict__ bhr,
                   __hip_bfloat16* __restrict__ ug16,
                   __hip_bfloat16* __restrict__ rg16)
{
    __shared__ __align__(16) float gh[32][644];            // 82432 B
    __shared__ __align__(16) float hf[32][204];            // 26112 B
    __shared__ __align__(16) __hip_bfloat16 h16[32][232];  // 14848 B

    const int tid = threadIdx.x;
    const bool isResp = (int)blockIdx.x >= 160;
    const int row0 = isResp ? ((int)blockIdx.x - 160) * 32 : (int)blockIdx.x * 32;
    const __hip_bfloat16* Wt = isResp ? Wr16 : Wu16;
    const float* bgate = isResp ? bhr : bhu;
    __hip_bfloat16* arch = isResp ? rg16 : ug16;

    for (int i = tid; i < 32 * 204; i += 512) ((float*)hf)[i] = 0.0f;
    for (int i = tid; i < 928; i += 512) ((uint4*)h16)[i] = make_uint4(0, 0, 0, 0);
    __syncthreads();

    const int wid = tid >> 6, lane = tid & 63;
    const int lrow = lane & 15, lk8 = (lane >> 4) * 8;
    const int drow = (lane >> 4) * 4, dcol = lane & 15;

    // ---- preload W fragments into registers (invariant over t) ----
    short8v Bf[5][7];
#pragma unroll
    for (int i = 0; i < 5; ++i) {
        const int j = (wid * 5 + i) * 16 + lrow;
#pragma unroll
        for (int kk = 0; kk < 7; ++kk)
            Bf[i][kk] = *(const short8v*)(Wt + (size_t)j * 224 + kk * 32 + lk8);
    }

    // gate task 0: rows 0..20; task 1 (tid<288): rows 20..31
    const int r0a = tid / 25,        c0a = (tid % 25) * 8;
    const int t1  = tid + 512;
    const int r0b = t1 / 25,         c0b = (t1 % 25) * 8;

    for (int t = 0; t < 50; ++t) {
        // ---- prefetch xp for BOTH gate tasks (hidden under MFMA phase) ----
        const int ga = row0 + r0a;
        const __hip_bfloat16* xpa = isResp
            ? (xpr16 + ((size_t)ga * 50 + t) * 600)
            : (EPu + (size_t)utt[ga * 50 + t] * 600);
        uint4 xra = *(const uint4*)(xpa + c0a);
        uint4 xza = *(const uint4*)(xpa + 200 + c0a);
        uint4 xna = *(const uint4*)(xpa + 400 + c0a);
        uint4 xrb, xzb, xnb;
        const int gb = row0 + r0b;
        if (tid < 288) {
            const __hip_bfloat16* xpb = isResp
                ? (xpr16 + ((size_t)gb * 50 + t) * 600)
                : (EPu + (size_t)utt[gb * 50 + t] * 600);
            xrb = *(const uint4*)(xpb + c0b);
            xzb = *(const uint4*)(xpb + 200 + c0b);
            xnb = *(const uint4*)(xpb + 400 + c0b);
        }

        // ---- MFMA phase: gh = h16 @ W^T (register B) ----
        f32x4 a0[5], a1[5];
#pragma unroll
        for (int i = 0; i < 5; ++i) {
            a0[i] = (f32x4){0.f, 0.f, 0.f, 0.f};
            a1[i] = (f32x4){0.f, 0.f, 0.f, 0.f};
        }
#pragma unroll
        for (int kk = 0; kk < 7; ++kk) {
            short8v A0 = *(const short8v*)(&h16[lrow][kk * 32 + lk8]);
            short8v A1 = *(const short8v*)(&h16[16 + lrow][kk * 32 + lk8]);
#pragma unroll
            for (int i = 0; i < 5; ++i) {
                a0[i] = __builtin_amdgcn_mfma_f32_16x16x32_bf16(A0, Bf[i][kk], a0[i], 0, 0, 0);
                a1[i] = __builtin_amdgcn_mfma_f32_16x16x32_bf16(A1, Bf[i][kk], a1[i], 0, 0, 0);
            }
        }
#pragma unroll
        for (int i = 0; i < 5; ++i) {
            const int j = (wid * 5 + i) * 16 + dcol;
#pragma unroll
            for (int r = 0; r < 4; ++r) {
                gh[drow + r][j] = a0[i][r];
                gh[16 + drow + r][j] = a1[i][r];
            }
        }
        __syncthreads();

        // ---- gate phase ----
        {   // task 0 (prefetched)
            const int row = r0a, c0 = c0a, grow = ga;
            const unsigned xr4[4] = { xra.x, xra.y, xra.z, xra.w };
            const unsigned xz4[4] = { xza.x, xza.y, xza.z, xza.w };
            const unsigned xn4[4] = { xna.x, xna.y, xna.z, xna.w };
            float hn[8];
#pragma unroll
            for (int j = 0; j < 8; ++j) {
                const int c = c0 + j;
                const float xr = (j & 1) ? bh(xr4[j >> 1]) : bl(xr4[j >> 1]);
                const float xz = (j & 1) ? bh(xz4[j >> 1]) : bl(xz4[j >> 1]);
                const float xn = (j & 1) ? bh(xn4[j >> 1]) : bl(xn4[j >> 1]);
                const float rr = sigm(xr + gh[row][c] + bgate[c]);
                const float zz = sigm(xz + gh[row][200 + c] + bgate[200 + c]);
                const float nn = tanhfast(xn + rr * (gh[row][400 + c] + bgate[400 + c]));
                hn[j] = (1.0f - zz) * nn + zz * hf[row][c];
            }
            *(float4*)(&hf[row][c0])     = (float4){hn[0], hn[1], hn[2], hn[3]};
            *(float4*)(&hf[row][c0 + 4]) = (float4){hn[4], hn[5], hn[6], hn[7]};
            uint4 pk;
            pk.x = packbf(hn[0], hn[1]); pk.y = packbf(hn[2], hn[3]);
            pk.z = packbf(hn[4], hn[5]); pk.w = packbf(hn[6], hn[7]);
            *(uint4*)(&h16[row][c0]) = pk;
            *(uint4*)(arch + ((size_t)grow * 50 + t) * 200 + c0) = pk;
        }
        if (tid < 288) {   // task 1 (prefetched)
            const int row = r0b, c0 = c0b, grow = gb;
            const unsigned xr4[4] = { xrb.x, xrb.y, xrb.z, xrb.w };
            const unsigned xz4[4] = { xzb.x, xzb.y, xzb.z, xzb.w };
            const unsigned xn4[4] = { xnb.x, xnb.y, xnb.z, xnb.w };
            float hn[8];
#pragma unroll
            for (int j = 0; j < 8; ++j) {
                const int c = c0 + j;
                const float xr = (j & 1) ? bh(xr4[j >> 1]) : bl(xr4[j >> 1]);
                const float xz = (j & 1) ? bh(xz4[j >> 1]) : bl(xz4[j >> 1]);
                const float xn = (j & 1) ? bh(xn4[j >> 1]) : bl(xn4[j >> 1]);
                const float rr = sigm(xr + gh[row][c] + bgate[c]);
                const float zz = sigm(xz + gh[row][200 + c] + bgate[200 + c]);
                const float nn = tanhfast(xn + rr * (gh[row][400 + c] + bgate[400 + c]));
                hn[j] = (1.0f - zz) * nn + zz * hf[row][c];
            }
            *(float4*)(&hf[row][c0])     = (float4){hn[0], hn[1], hn[2], hn[3]};
            *(float4*)(&hf[row][c0 + 4]) = (float4){hn[4], hn[5], hn[6], hn[7]};
            uint4 pk;
            pk.x = packbf(hn[0], hn[1]); pk.y = packbf(hn[2], hn[3]);
            pk.z = packbf(hn[4], hn[5]); pk.w = packbf(hn[6], hn[7]);
            *(uint4*)(&h16[row][c0]) = pk;
            *(uint4*)(arch + ((size_t)grow * 50 + t) * 200 + c0) = pk;
        }
        __syncthreads();
    }
}

// ---------------------------------------------------------------------------
// Fused m1/m2 match (MFMA) + conv3x3(2->8)+relu+maxpool3x3 per (b,u).
// Both m1 operands gathered directly from emb16 (utt rows / resp rows).
// ---------------------------------------------------------------------------
__global__ __launch_bounds__(256)
void match_conv_pool(const int* __restrict__ utt, const int* __restrict__ resp,
                     const __hip_bfloat16* __restrict__ emb16,
                     const __hip_bfloat16* __restrict__ ug16,
                     const __hip_bfloat16* __restrict__ rgA16,
                     const float* __restrict__ cw, const float* __restrict__ cb,
                     __hip_bfloat16* __restrict__ pooled16)
{
    const int bu = blockIdx.x, b = bu / 10;
    __shared__ __align__(16) __hip_bfloat16 As[64 * 232];
    __shared__ __align__(16) __hip_bfloat16 Bs[64 * 232];
    __shared__ float m[2][50][50];
    __shared__ float w[144];
    __shared__ float bsh[8];
    const int tid = threadIdx.x;
    if (tid < 144) w[tid] = cw[tid];
    if (tid >= 144 && tid < 152) bsh[tid - 144] = cb[tid - 144];

    for (int idx = tid; idx < 64 * 29; idx += 256) {
        int r = idx / 29, q = idx - r * 29;
        uint4 av = make_uint4(0, 0, 0, 0), bv = make_uint4(0, 0, 0, 0);
        if (r < 50 && q < 25) {
            av = *(const uint4*)(emb16 + (size_t)utt[bu * 50 + r] * 200 + q * 8);
            bv = *(const uint4*)(emb16 + (size_t)resp[b * 50 + r] * 200 + q * 8);
        }
        *(uint4*)(As + r * 232 + q * 8) = av;
        *(uint4*)(Bs + r * 232 + q * 8) = bv;
    }
    __syncthreads();

    const int wid = tid >> 6, lane = tid & 63;
    const int wm = (wid >> 1) * 32, wn = (wid & 1) * 32;
    const int lrow = lane & 15, lk8 = (lane >> 4) * 8;
    const int drow = (lane >> 4) * 4, dcol = lane & 15;

#pragma unroll 1
    for (int ch = 0; ch < 2; ++ch) {
        f32x4 acc00 = {0.f, 0.f, 0.f, 0.f}, acc01 = {0.f, 0.f, 0.f, 0.f};
        f32x4 acc10 = {0.f, 0.f, 0.f, 0.f}, acc11 = {0.f, 0.f, 0.f, 0.f};
#pragma unroll
        for (int kk = 0; kk < 7; ++kk) {
            const int kb = kk * 32 + lk8;
            short8v a0 = *(const short8v*)(As + (wm + lrow) * 232 + kb);
            short8v a1 = *(const short8v*)(As + (wm + 16 + lrow) * 232 + kb);
            short8v b0 = *(const short8v*)(Bs + (wn + lrow) * 232 + kb);
            short8v b1 = *(const short8v*)(Bs + (wn + 16 + lrow) * 232 + kb);
            acc00 = __builtin_amdgcn_mfma_f32_16x16x32_bf16(a0, b0, acc00, 0, 0, 0);
            acc01 = __builtin_amdgcn_mfma_f32_16x16x32_bf16(a0, b1, acc01, 0, 0, 0);
            acc10 = __builtin_amdgcn_mfma_f32_16x16x32_bf16(a1, b0, acc10, 0, 0, 0);
            acc11 = __builtin_amdgcn_mfma_f32_16x16x32_bf16(a1, b1, acc11, 0, 0, 0);
        }
#pragma unroll
        for (int fm = 0; fm < 2; ++fm) {
#pragma unroll
            for (int fn = 0; fn < 2; ++fn) {
                const f32x4 av = (fm == 0) ? (fn == 0 ? acc00 : acc01)
                                           : (fn == 0 ? acc10 : acc11);
                const int gcol = wn + fn * 16 + dcol;
                if (gcol >= 50) continue;
#pragma unroll
                for (int r = 0; r < 4; ++r) {
                    const int grow = wm + fm * 16 + drow + r;
                    if (grow < 50) m[ch][grow][gcol] = av[r];
                }
            }
        }
        __syncthreads();
        if (ch == 0) {
            for (int idx = tid; idx < 50 * 25; idx += 256) {
                int r = idx / 25, q = idx - r * 25;
                *(uint4*)(As + r * 232 + q * 8) =
                    *(const uint4*)(ug16 + (size_t)bu * 10000 + (size_t)r * 200 + q * 8);
                *(uint4*)(Bs + r * 232 + q * 8) =
                    *(const uint4*)(rgA16 + (size_t)b * 10000 + (size_t)r * 200 + q * 8);
            }
            __syncthreads();
        }
    }

#pragma unroll
    for (int k = 0; k < 8; ++k) {
        const int o = tid + k * 256;
        const int c = o >> 8, ph = (o >> 4) & 15, pw = o & 15;
        float mx = -1e30f;
#pragma unroll
        for (int p = 0; p < 3; ++p)
#pragma unroll
            for (int q = 0; q < 3; ++q) {
                const int y = ph * 3 + p, x = pw * 3 + q;
                float s = bsh[c];
#pragma unroll
                for (int ci = 0; ci < 2; ++ci)
#pragma unroll
                    for (int dy = 0; dy < 3; ++dy)
#pragma unroll
                        for (int dx = 0; dx < 3; ++dx)
                            s = fmaf(w[(c * 2 + ci) * 9 + dy * 3 + dx],
                                     m[ci][y + dy][x + dx], s);
                s = fmaxf(s, 0.0f);
                mx = fmaxf(mx, s);
            }
        pooled16[(size_t)bu * 2048 + o] = __float2bfloat16(mx);
    }
}

// ---------------------------------------------------------------------------
__global__ __launch_bounds__(256)
void final_gru(const float* __restrict__ xpf, const float* __restrict__ WTf,
               const float* __restrict__ bhf, const float* __restrict__ fw,
               const float* __restrict__ fb, float* __restrict__ out)
{
    const int blk = blockIdx.x;
    const int tid = threadIdx.x;
    __shared__ float h[2][201];
    for (int i = tid; i < 402; i += 256) ((float*)h)[i] = 0.0f;
    __syncthreads();
    const int rr = tid / 100;
    const int j0 = 2 * (tid % 100);
    for (int t = 0; t < 10; ++t) {
        float cR[2] = {}, cZ[2] = {}, cN[2] = {};
        if (tid < 200) {
#pragma unroll 2
            for (int e = 0; e < 200; ++e) {
                const float* w = WTf + (size_t)e * 600;
                float2 wr = *(const float2*)(w + j0);
                float2 wz = *(const float2*)(w + 200 + j0);
                float2 wn = *(const float2*)(w + 400 + j0);
                float hv = h[rr][e];
                cR[0] = fmaf(hv, wr.x, cR[0]); cR[1] = fmaf(hv, wr.y, cR[1]);
                cZ[0] = fmaf(hv, wz.x, cZ[0]); cZ[1] = fmaf(hv, wz.y, cZ[1]);
                cN[0] = fmaf(hv, wn.x, cN[0]); cN[1] = fmaf(hv, wn.y, cN[1]);
            }
        }
        __syncthreads();
        if (tid < 200) {
            const float* xp = xpf + ((size_t)(blk * 2 + rr) * 10 + t) * 600;
#pragma unroll
            for (int j = 0; j < 2; ++j) {
                const int c = j0 + j;
                float rrg = sigm(xp[c] + cR[j] + bhf[c]);
                float zz = sigm(xp[200 + c] + cZ[j] + bhf[200 + c]);
                float nn = tanhfast(xp[400 + c] + rrg * (cN[j] + bhf[400 + c]));
                h[rr][c] = (1.0f - zz) * nn + zz * h[rr][c];
            }
        }
        __syncthreads();
    }
    if (tid < 2) {
        float s = fb[0];
        for (int k = 0; k < 200; ++k) s = fmaf(h[tid][k], fw[k], s);
        out[blk * 2 + tid] = sigm(s);
    }
}

__global__ __launch_bounds__(256)
void fill_out(float* __restrict__ out)
{
    int i = blockIdx.x * 256 + threadIdx.x;
    if (i < 512) out[i] = 0.0f;
}

// ---------------------------------------------------------------------------
extern "C" void kernel_launch(void* const* d_in, const int* in_sizes, int n_in,
                              void* d_out, int out_size, void* d_ws, size_t ws_size,
                              hipStream_t stream)
{
    const int*   utt    = (const int*)d_in[0];
    const int*   resp   = (const int*)d_in[1];
    const float* emb    = (const float*)d_in[2];
    const float* W_ih_u = (const float*)d_in[3];
    const float* W_hh_u = (const float*)d_in[4];
    const float* b_ih_u = (const float*)d_in[5];
    const float* b_hh_u = (const float*)d_in[6];
    const float* W_ih_r = (const float*)d_in[7];
    const float* W_hh_r = (const float*)d_in[8];
    const float* b_ih_r = (const float*)d_in[9];
    const float* b_hh_r = (const float*)d_in[10];
    const float* conv_w = (const float*)d_in[11];
    const float* conv_b = (const float*)d_in[12];
    const float* lin_w  = (const float*)d_in[13];
    const float* lin_b  = (const float*)d_in[14];
    const float* Amat   = (const float*)d_in[15];
    const float* W_ih_f = (const float*)d_in[16];
    const float* W_hh_f = (const float*)d_in[17];
    const float* b_ih_f = (const float*)d_in[18];
    const float* b_hh_f = (const float*)d_in[19];
    const float* flin_w = (const float*)d_in[20];
    const float* flin_b = (const float*)d_in[21];
    float* out = (float*)d_out;
    float* ws  = (float*)d_ws;

    size_t off = 0;
    auto alloc = [&](size_t n) { float* p = ws + off; off += (n + 63) & ~((size_t)63); return p; };
    float* WT_f   = alloc(120000);
    float* Wu16f  = alloc(71680);      // [640,224] bf16
    float* Wr16f  = alloc(71680);      // [640,224] bf16
    float* emb16f = alloc(5000000);    // [50000,200] bf16 = 20 MB
    float* EPuf   = alloc(15000000);   // [50000,600] bf16; post-scan: pooled16
    float* xprf   = alloc(7680000);    // [25600,600] bf16; post-scan: mv16/xpf
    float* ug16f  = alloc(25600000);   // [5120,50,200] bf16
    float* rg16f  = alloc(2560000);    // [512,50,200] bf16
    float* rgA16f = alloc(2560000);    // [25600,200] bf16
    // total ~58.7M floats = 235 MB

    if (off * sizeof(float) > ws_size) {
        hipLaunchKernelGGL(fill_out, dim3(2), dim3(256), 0, stream, out);
        return;
    }

    __hip_bfloat16* Wu16  = (__hip_bfloat16*)Wu16f;
    __hip_bfloat16* Wr16  = (__hip_bfloat16*)Wr16f;
    __hip_bfloat16* emb16 = (__hip_bfloat16*)emb16f;
    __hip_bfloat16* EPu   = (__hip_bfloat16*)EPuf;
    __hip_bfloat16* xpr16 = (__hip_bfloat16*)xprf;
    __hip_bfloat16* ug16  = (__hip_bfloat16*)ug16f;
    __hip_bfloat16* rg16  = (__hip_bfloat16*)rg16f;
    __hip_bfloat16* rgA16 = (__hip_bfloat16*)rgA16f;
    __hip_bfloat16* pooled16 = (__hip_bfloat16*)EPuf;   // [5120,2048] bf16 (EPu dead)
    __hip_bfloat16* mv16     = (__hip_bfloat16*)xprf;   // [5120,50] bf16 (xpr dead)
    float* xpf = xprf + 400000;                          // [5120,600] f32

    // 1. one-pass conversions: W_hh_f transpose, Whh bf16 pack, emb bf16
    hipLaunchKernelGGL(transpose_wf, dim3(469), dim3(256), 0, stream, W_hh_f, WT_f);
    hipLaunchKernelGGL(pack_whh, dim3(560), dim3(256), 0, stream,
                       W_hh_u, W_hh_r, Wu16, Wr16);
    hipLaunchKernelGGL(conv_emb16, dim3(19532), dim3(256), 0, stream, emb, emb16);
    // 2. EPu = bf16(emb16 @ W_ih_u^T + b_ih_u)  [MFMA, bf16 A]
    hipLaunchKernelGGL(gemm_mfma, dim3(782, 10), dim3(256), 0, stream,
                       (const void*)emb16, 1, (const int*)nullptr, W_ih_u, b_ih_u,
                       EPu, 50000, 600);
    // 3. xpr16 = bf16(emb16[resp] @ W_ih_r^T + b_ih_r)  [MFMA, bf16 A gather]
    hipLaunchKernelGGL(gemm_mfma, dim3(400, 10), dim3(256), 0, stream,
                       (const void*)emb16, 1, resp, W_ih_r, b_ih_r,
                       xpr16, 25600, 600);
    // 4. persistent MFMA dual-GRU scan (r13 config)
    hipLaunchKernelGGL(scan_gru_mfma, dim3(176), dim3(512), 0, stream,
                       utt, EPu, xpr16, Wu16, Wr16, b_hh_u, b_hh_r, ug16, rg16);
    // 5. rgA16 = bf16(rg @ Amat^T)  [MFMA]
    hipLaunchKernelGGL(gemm_mfma, dim3(400, 4), dim3(256), 0, stream,
                       (const void*)rg16, 1, (const int*)nullptr, Amat,
                       (const float*)nullptr, rgA16, 25600, 200);
    // 6. fused match (MFMA, emb16-gathered operands) + conv + pool
    hipLaunchKernelGGL(match_conv_pool, dim3(5120), dim3(256), 0, stream,
                       utt, resp, emb16, ug16, rgA16, conv_w, conv_b, pooled16);
    // 7. mv16 = tanh(pooled16 @ lin_w^T + lin_b)  [MFMA, K=2048]
    hipLaunchKernelGGL(gemm_mfma_k, dim3(80, 1), dim3(256), 0, stream,
                       (const void*)pooled16, 1, lin_w, lin_b,
                       (void*)mv16, 1, 5120, 50, 2048, 1);
    // 8. xpf = mv16 @ W_ih_f^T + b_ih_f  [MFMA, K=50]
    hipLaunchKernelGGL(gemm_mfma_k, dim3(80, 10), dim3(256), 0, stream,
                       (const void*)mv16, 1, W_ih_f, b_ih_f,
                       (void*)xpf, 0, 5120, 600, 50, 0);
    // 9. final GRU + logit + sigmoid
    hipLaunchKernelGGL(final_gru, dim3(256), dim3(256), 0, stream,
                       xpf, WT_f, b_hh_f, flin_w, flin_b, out);
}